// Round 3
// baseline (828.356 us; speedup 1.0000x reference)
//
#include <hip/hip_runtime.h>
#include <hip/hip_bf16.h>

#define N_NODES 50000
#define N_EDGES 1600000
#define NREL    16
#define DIM     64

#define BKT_SH  5
#define BKT_SZ  32
#define NBKT    1563          // ceil(50000/32) buckets of 32 dst nodes
#define P1_CHUNK 2048
#define P1_GRID  782          // ceil(1.6M/2048)
#define SEG_PAD  256          // per-bucket slack: 16-align + 16 segs * <=15 pad
#define EMAX    (N_EDGES + NBKT * SEG_PAD)   // 2,000,128 edge slots
#define PREP_HBLK 3125        // 3.2M h elems / 1024 per block

typedef __attribute__((ext_vector_type(8))) short short8;
typedef __attribute__((ext_vector_type(4))) float float4v;
typedef __attribute__((ext_vector_type(4))) unsigned short ushort4v;

template<int IS_F32>
__device__ __forceinline__ float ldx(const void* p, size_t i) {
    if (IS_F32) {
        return ((const float*)p)[i];
    } else {
        unsigned short u = ((const unsigned short*)p)[i];
        return __uint_as_float(((unsigned)u) << 16);
    }
}

__device__ __forceinline__ float bfbits2f(unsigned short u) {
    return __uint_as_float(((unsigned)u) << 16);
}

__device__ __forceinline__ unsigned short f2bfbits(float v) {
    __hip_bfloat16 b = __float2bfloat16(v);
    unsigned short us; __builtin_memcpy(&us, &b, 2);
    return us;
}

// ---------------------------------------------------------------------------
// Dtype detector (proven): flag=1 if f32 dataset, 0 if bf16.
// ---------------------------------------------------------------------------
__global__ __launch_bounds__(1024) void k_detect(
    const float* __restrict__ norm_f, int* __restrict__ flag)
{
    __shared__ int sbad;
    if (threadIdx.x == 0) sbad = 0;
    __syncthreads();
    float v = norm_f[threadIdx.x];
    int bad = (v != v || fabsf(v) > 1e3f) ? 1 : 0;
    if (bad) atomicOr(&sbad, 1);
    __syncthreads();
    if (threadIdx.x == 0) *flag = sbad ? 0 : 1;
}

// ---------------------------------------------------------------------------
// Bucket histogram (proven structure; bucket = dst>>5).
// ---------------------------------------------------------------------------
__global__ __launch_bounds__(256) void k_bhist(
    const int* __restrict__ dst, int* __restrict__ H)
{
    __shared__ int hist[NBKT];
    for (int i = threadIdx.x; i < NBKT; i += 256) hist[i] = 0;
    __syncthreads();
    const int e0 = blockIdx.x * P1_CHUNK;
    for (int i = threadIdx.x; i < P1_CHUNK; i += 256) {
        int e = e0 + i;
        if (e < N_EDGES) atomicAdd(&hist[dst[e] >> BKT_SH], 1);
    }
    __syncthreads();
    for (int b = threadIdx.x; b < NBKT; b += 256)
        H[blockIdx.x * NBKT + b] = hist[b];
}

__global__ __launch_bounds__(256) void k_bscan1(
    const int* __restrict__ H, int* __restrict__ OT, int* __restrict__ tot)
{
    __shared__ int col[P1_GRID];
    const int b = blockIdx.x;
    for (int i = threadIdx.x; i < P1_GRID; i += 256)
        col[i] = H[i * NBKT + b];
    __syncthreads();
    if (threadIdx.x < 64) {
        const int lane = threadIdx.x;
        int carry = 0;
        for (int chunk = 0; chunk < (P1_GRID + 63) / 64; ++chunk) {
            int i = chunk * 64 + lane;
            int c = (i < P1_GRID) ? col[i] : 0;
            int incl = c;
#pragma unroll
            for (int off = 1; off < 64; off <<= 1) {
                int t = __shfl_up(incl, off, 64);
                if (lane >= off) incl += t;
            }
            if (i < P1_GRID) col[i] = carry + incl - c;
            carry += __shfl(incl, 63, 64);
        }
        if (lane == 0) tot[b] = carry;
    }
    __syncthreads();
    for (int i = threadIdx.x; i < P1_GRID; i += 256)
        OT[(size_t)b * P1_GRID + i] = col[i];
}

__global__ __launch_bounds__(64) void k_bscan2(
    const int* __restrict__ tot, int* __restrict__ base)
{
    const int lane = threadIdx.x;
    int carry = 0;
    for (int chunk = 0; chunk < (NBKT + 63) / 64; ++chunk) {
        int i = chunk * 64 + lane;
        int c = (i < NBKT) ? tot[i] : 0;
        int incl = c;
#pragma unroll
        for (int off = 1; off < 64; off <<= 1) {
            int t = __shfl_up(incl, off, 64);
            if (lane >= off) incl += t;
        }
        if (i < NBKT) base[i] = carry + incl - c;
        carry += __shfl(incl, 63, 64);
    }
    if (lane == 0) base[NBKT] = carry;   // == N_EDGES
}

// ---------------------------------------------------------------------------
// P1 (proven): multisplit into bucket runs, deterministic reservation.
// rec: [7:0]=dst&31, [23:8]=src, [27:24]=rel, [47:32]=norm bf16.
// ---------------------------------------------------------------------------
template<int IS_F32>
__device__ __forceinline__ void p1_body(
    const int* __restrict__ src, const int* __restrict__ dst,
    const int* __restrict__ rel, const void* __restrict__ norm_raw,
    const int* __restrict__ base, const int* __restrict__ OT,
    unsigned long long* __restrict__ R, int* curs)
{
    const int blk = blockIdx.x;
    for (int b = threadIdx.x; b < NBKT; b += 256)
        curs[b] = base[b] + OT[(size_t)b * P1_GRID + blk];
    __syncthreads();
    const int e0 = blk * P1_CHUNK;
    for (int i = threadIdx.x; i < P1_CHUNK; i += 256) {
        int e = e0 + i;
        if (e >= N_EDGES) continue;
        int d = dst[e];
        int pos = atomicAdd(&curs[d >> BKT_SH], 1);
        unsigned short nb = f2bfbits(ldx<IS_F32>(norm_raw, e));
        unsigned long long rec =
              (unsigned long long)(d & (BKT_SZ - 1))
            | ((unsigned long long)(unsigned)src[e] << 8)
            | ((unsigned long long)(unsigned)rel[e] << 24)
            | ((unsigned long long)nb << 32);
        R[pos] = rec;
    }
}

__global__ __launch_bounds__(256) void k_p1(
    const int* __restrict__ src, const int* __restrict__ dst,
    const int* __restrict__ rel, const void* __restrict__ norm_raw,
    const int* __restrict__ base, const int* __restrict__ OT,
    unsigned long long* __restrict__ R, const int* __restrict__ flag)
{
    __shared__ int curs[NBKT];
    if (*flag) p1_body<1>(src, dst, rel, norm_raw, base, OT, R, curs);
    else       p1_body<0>(src, dst, rel, norm_raw, base, OT, R, curs);
}

// ---------------------------------------------------------------------------
// P2SEG (proven): per bucket, split run into 16 rel segments, padded to x16.
// packed2: [7:0]=dstlocal, [23:8]=src. Pad entries are all-zero (norm=0).
// ---------------------------------------------------------------------------
__global__ __launch_bounds__(256) void k_p2seg(
    const int* __restrict__ base,
    const unsigned long long* __restrict__ R,
    unsigned* __restrict__ packed2,
    unsigned short* __restrict__ normS,
    int* __restrict__ segBase,
    int* __restrict__ segCnt)
{
    __shared__ int cnt[16], curs[16], sbl[16];
    const int tid = threadIdx.x;
    if (tid < 16) { cnt[tid] = 0; curs[tid] = 0; }
    __syncthreads();

    const int b  = blockIdx.x;
    const int c0 = base[b], c1 = base[b + 1];

    for (int i = c0 + tid; i < c1; i += 256)
        atomicAdd(&cnt[(int)((R[i] >> 24) & 15)], 1);
    __syncthreads();

    if (tid == 0) {
        int g = ((c0 + 15) & ~15) + b * SEG_PAD;
        for (int r = 0; r < 16; ++r) {
            sbl[r] = g;
            g += (cnt[r] + 15) & ~15;
        }
    }
    __syncthreads();
    if (tid < 16) {
        segBase[b * 16 + tid] = sbl[tid];
        segCnt[b * 16 + tid]  = cnt[tid];
    }

    for (int i = c0 + tid; i < c1; i += 256) {
        unsigned long long rec = R[i];
        int r = (int)((rec >> 24) & 15);
        int pos = sbl[r] + atomicAdd(&curs[r], 1);
        packed2[pos] = (unsigned)(rec & 0xFFFFFFu);
        normS[pos]   = (unsigned short)(rec >> 32);
    }
    __syncthreads();

    {   // pads: <=15 per segment, 16 segments -> 256 candidate slots
        int r = tid >> 4, j = tid & 15;
        int c = cnt[r], p = (c + 15) & ~15;
        if (j < p - c) {
            int pos = sbl[r] + c + j;
            packed2[pos] = 0;
            normS[pos]   = 0;
        }
    }
}

// ---------------------------------------------------------------------------
// PREP (proven): h -> bf16 copy (6.4 MB gather target) and W -> pre-swizzled
// bf16 B-fragment layout (stride 40).
// ---------------------------------------------------------------------------
__global__ __launch_bounds__(256) void k_prep(
    const void* __restrict__ h_raw, const void* __restrict__ w_raw,
    unsigned short* __restrict__ hbf, unsigned short* __restrict__ Wswz,
    const int* __restrict__ flag)
{
    const int f = *flag;
    const int blk = blockIdx.x;
    if (blk < PREP_HBLK) {
        int i0 = blk * 1024 + threadIdx.x * 4;
        if (f) {
            float4 v = *(const float4*)((const float*)h_raw + i0);
            ushort4v o;
            o[0] = f2bfbits(v.x); o[1] = f2bfbits(v.y);
            o[2] = f2bfbits(v.z); o[3] = f2bfbits(v.w);
            *(ushort4v*)(hbf + i0) = o;
        } else {
            *(uint2*)(hbf + i0) = *(const uint2*)((const unsigned short*)h_raw + i0);
        }
    } else {
        int rel = blk - PREP_HBLK;
        for (int idx = threadIdx.x; idx < 4096; idx += 256) {
            int d = idx >> 6, o = idx & 63;
            float wv = f ? ((const float*)w_raw)[(size_t)((rel << 6) + d) * 64 + o]
                         : bfbits2f(((const unsigned short*)w_raw)[(size_t)((rel << 6) + d) * 64 + o]);
            int c = d >> 5, q = (d >> 3) & 3, j = d & 7;
            Wswz[(size_t)rel * 5120 + ((c << 6) + o) * 40 + q * 8 + j] = f2bfbits(wv);
        }
    }
}

// ---------------------------------------------------------------------------
// K_FUSED v2: fully scalarized (no indexable register arrays -> no scratch),
// hardware ds_add_f32 via unsafeAtomicAdd, metadata prefetch pipeline.
// Waves own disjoint rel segments; W B-frags reg-resident per segment.
// ---------------------------------------------------------------------------
__global__ __launch_bounds__(256) void k_fused(
    const unsigned* __restrict__ packed2,
    const unsigned short* __restrict__ normS,
    const unsigned short* __restrict__ hbf,
    const unsigned short* __restrict__ Wswz,
    const int* __restrict__ segBase,
    const int* __restrict__ segCnt,
    void* __restrict__ out, const int* __restrict__ flag)
{
    __shared__ float outacc[BKT_SZ * 66];
    const int tid  = threadIdx.x;
    const int lane = tid & 63, wave = tid >> 6;
    const int n15  = lane & 15, quad = lane >> 4;
    const int b    = blockIdx.x;

    for (int i = tid; i < BKT_SZ * 66; i += 256) outacc[i] = 0.f;
    __syncthreads();

    for (int r = wave; r < 16; r += 4) {
        const int sb  = segBase[b * 16 + r];
        const int cnt = segCnt[b * 16 + r];
        if (cnt == 0) continue;
        const int ng = (cnt + 15) >> 4;

        // B fragments: named registers, direct short8 loads (16B-aligned).
        const unsigned short* wp = Wswz + (size_t)r * 5120;
        short8 b00 = *(const short8*)(wp + (0 * 16 + n15) * 40 + quad * 8);
        short8 b01 = *(const short8*)(wp + (1 * 16 + n15) * 40 + quad * 8);
        short8 b02 = *(const short8*)(wp + (2 * 16 + n15) * 40 + quad * 8);
        short8 b03 = *(const short8*)(wp + (3 * 16 + n15) * 40 + quad * 8);
        short8 b10 = *(const short8*)(wp + ((64 + 0 * 16) + n15) * 40 + quad * 8);
        short8 b11 = *(const short8*)(wp + ((64 + 1 * 16) + n15) * 40 + quad * 8);
        short8 b12 = *(const short8*)(wp + ((64 + 2 * 16) + n15) * 40 + quad * 8);
        short8 b13 = *(const short8*)(wp + ((64 + 3 * 16) + n15) * 40 + quad * 8);

        // Pipeline: metadata for group g loaded in iteration g-1.
        unsigned pk = packed2[sb + n15];
        uint4    pm = *(const uint4*)(packed2 + sb + quad * 4);
        ushort4v nm = *(const ushort4v*)(normS + sb + quad * 4);

        for (int g = 0; g < ng; ++g) {
            // A rows for current group (depends on pk from previous iter).
            const unsigned short* hp = hbf + (size_t)(pk >> 8) * 64;
            short8 a0 = *(const short8*)(hp + quad * 8);
            short8 a1 = *(const short8*)(hp + 32 + quad * 8);

            // Prefetch next group's metadata (wave-uniform branch).
            unsigned pk_n = 0; uint4 pm_n; ushort4v nm_n;
            pm_n.x = pm_n.y = pm_n.z = pm_n.w = 0;
            nm_n[0] = nm_n[1] = nm_n[2] = nm_n[3] = 0;
            if (g + 1 < ng) {
                const int e1 = sb + (g + 1) * 16;
                pk_n = packed2[e1 + n15];
                pm_n = *(const uint4*)(packed2 + e1 + quad * 4);
                nm_n = *(const ushort4v*)(normS + e1 + quad * 4);
            }

            float4v acc0 = (float4v){0.f, 0.f, 0.f, 0.f};
            float4v acc1 = (float4v){0.f, 0.f, 0.f, 0.f};
            float4v acc2 = (float4v){0.f, 0.f, 0.f, 0.f};
            float4v acc3 = (float4v){0.f, 0.f, 0.f, 0.f};
            acc0 = __builtin_amdgcn_mfma_f32_16x16x32_bf16(a0, b00, acc0, 0, 0, 0);
            acc1 = __builtin_amdgcn_mfma_f32_16x16x32_bf16(a0, b01, acc1, 0, 0, 0);
            acc2 = __builtin_amdgcn_mfma_f32_16x16x32_bf16(a0, b02, acc2, 0, 0, 0);
            acc3 = __builtin_amdgcn_mfma_f32_16x16x32_bf16(a0, b03, acc3, 0, 0, 0);
            acc0 = __builtin_amdgcn_mfma_f32_16x16x32_bf16(a1, b10, acc0, 0, 0, 0);
            acc1 = __builtin_amdgcn_mfma_f32_16x16x32_bf16(a1, b11, acc1, 0, 0, 0);
            acc2 = __builtin_amdgcn_mfma_f32_16x16x32_bf16(a1, b12, acc2, 0, 0, 0);
            acc3 = __builtin_amdgcn_mfma_f32_16x16x32_bf16(a1, b13, acc3, 0, 0, 0);

            const float nf0 = bfbits2f(nm[0]), nf1 = bfbits2f(nm[1]);
            const float nf2 = bfbits2f(nm[2]), nf3 = bfbits2f(nm[3]);
            const int d0 = pm.x & (BKT_SZ - 1), d1 = pm.y & (BKT_SZ - 1);
            const int d2 = pm.z & (BKT_SZ - 1), d3 = pm.w & (BKT_SZ - 1);

            const int c0 = 0 * 16 + n15, c1 = 1 * 16 + n15;
            const int c2 = 2 * 16 + n15, c3 = 3 * 16 + n15;
            unsafeAtomicAdd(&outacc[d0 * 66 + c0], acc0[0] * nf0);
            unsafeAtomicAdd(&outacc[d0 * 66 + c1], acc1[0] * nf0);
            unsafeAtomicAdd(&outacc[d0 * 66 + c2], acc2[0] * nf0);
            unsafeAtomicAdd(&outacc[d0 * 66 + c3], acc3[0] * nf0);
            unsafeAtomicAdd(&outacc[d1 * 66 + c0], acc0[1] * nf1);
            unsafeAtomicAdd(&outacc[d1 * 66 + c1], acc1[1] * nf1);
            unsafeAtomicAdd(&outacc[d1 * 66 + c2], acc2[1] * nf1);
            unsafeAtomicAdd(&outacc[d1 * 66 + c3], acc3[1] * nf1);
            unsafeAtomicAdd(&outacc[d2 * 66 + c0], acc0[2] * nf2);
            unsafeAtomicAdd(&outacc[d2 * 66 + c1], acc1[2] * nf2);
            unsafeAtomicAdd(&outacc[d2 * 66 + c2], acc2[2] * nf2);
            unsafeAtomicAdd(&outacc[d2 * 66 + c3], acc3[2] * nf2);
            unsafeAtomicAdd(&outacc[d3 * 66 + c0], acc0[3] * nf3);
            unsafeAtomicAdd(&outacc[d3 * 66 + c1], acc1[3] * nf3);
            unsafeAtomicAdd(&outacc[d3 * 66 + c2], acc2[3] * nf3);
            unsafeAtomicAdd(&outacc[d3 * 66 + c3], acc3[3] * nf3);

            pk = pk_n; pm = pm_n; nm = nm_n;
        }
    }
    __syncthreads();

    const int v0n = b << BKT_SH;
    const int nn  = min(BKT_SZ, N_NODES - v0n);
    const int f   = *flag;
    for (int idx = tid; idx < nn * 64; idx += 256) {
        int row = idx >> 6, col = idx & 63;
        float rv = fmaxf(outacc[row * 66 + col], 0.f);
        size_t ob = (size_t)(v0n + row) * 64 + col;
        if (f) ((float*)out)[ob] = rv;
        else   ((unsigned short*)out)[ob] = f2bfbits(rv);
    }
}

// ---------------------------------------------------------------------------
extern "C" void kernel_launch(void* const* d_in, const int* in_sizes, int n_in,
                              void* d_out, int out_size, void* d_ws, size_t ws_size,
                              hipStream_t stream)
{
    const void* h      = d_in[0];
    const void* weight = d_in[1];
    const void* norm   = d_in[2];
    const int* src = (const int*)d_in[3];
    const int* dst = (const int*)d_in[4];
    const int* rel = (const int*)d_in[5];

    char* w = (char*)d_ws;
    int* flag = (int*)w;                        w += 256;
    int* base = (int*)w;                        w += ((NBKT + 1) * 4 + 255) / 256 * 256;
    int* tot  = (int*)w;                        w += (NBKT * 4 + 255) / 256 * 256;
    int* H    = (int*)w;                        w += ((size_t)P1_GRID * NBKT * 4 + 255) / 256 * 256;
    int* OT   = (int*)w;                        w += ((size_t)NBKT * P1_GRID * 4 + 255) / 256 * 256;
    int* segBase = (int*)w;                     w += (NBKT * 16 * 4 + 255) / 256 * 256;
    int* segCnt  = (int*)w;                     w += (NBKT * 16 * 4 + 255) / 256 * 256;
    unsigned long long* R = (unsigned long long*)w;  w += (size_t)N_EDGES * 8;
    unsigned* packed2 = (unsigned*)w;           w += (size_t)EMAX * 4;
    unsigned short* normS = (unsigned short*)w; w += (size_t)EMAX * 2;
    unsigned short* hbf = (unsigned short*)w;   w += (size_t)N_NODES * DIM * 2;
    unsigned short* Wswz = (unsigned short*)w;  w += (size_t)NREL * 5120 * 2;

    k_detect<<<1, 1024, 0, stream>>>((const float*)norm, flag);

    k_bhist<<<P1_GRID, 256, 0, stream>>>(dst, H);
    k_bscan1<<<NBKT, 256, 0, stream>>>(H, OT, tot);
    k_bscan2<<<1, 64, 0, stream>>>(tot, base);

    k_p1<<<P1_GRID, 256, 0, stream>>>(src, dst, rel, norm, base, OT, R, flag);
    k_p2seg<<<NBKT, 256, 0, stream>>>(base, R, packed2, normS, segBase, segCnt);

    k_prep<<<PREP_HBLK + NREL, 256, 0, stream>>>(h, weight, hbf, Wswz, flag);

    k_fused<<<NBKT, 256, 0, stream>>>(packed2, normS, hbf, Wswz,
                                      segBase, segCnt, d_out, flag);
}

// Round 4
// 261.372 us; speedup vs baseline: 3.1693x; 3.1693x over previous
//
#include <hip/hip_runtime.h>
#include <hip/hip_bf16.h>

#define N_NODES 50000
#define N_EDGES 1600000
#define NREL    16
#define DIM     64

#define BKT_SH  4
#define BKT_SZ  16
#define NBKT    3125          // 50000/16 exact
#define P1_CHUNK 4096
#define P1_GRID  391          // ceil(1.6M/4096)
#define SEG_PAD  544          // 31 (align) + 16 segs * <=31 pad = 527, rounded to x32
#define EMAX    (N_EDGES + NBKT * SEG_PAD + 2048)   // 3,302,048 edge slots
#define PREP_HBLK 3125        // 3.2M h elems / 1024 per block

typedef __attribute__((ext_vector_type(8))) short short8;
typedef __attribute__((ext_vector_type(4))) float float4v;
typedef __attribute__((ext_vector_type(4))) unsigned short ushort4v;

template<int IS_F32>
__device__ __forceinline__ float ldx(const void* p, size_t i) {
    if (IS_F32) {
        return ((const float*)p)[i];
    } else {
        unsigned short u = ((const unsigned short*)p)[i];
        return __uint_as_float(((unsigned)u) << 16);
    }
}

__device__ __forceinline__ float bfbits2f(unsigned short u) {
    return __uint_as_float(((unsigned)u) << 16);
}

__device__ __forceinline__ unsigned short f2bfbits(float v) {
    __hip_bfloat16 b = __float2bfloat16(v);
    unsigned short us; __builtin_memcpy(&us, &b, 2);
    return us;
}

// ---------------------------------------------------------------------------
// Dtype detector (proven): flag=1 if f32 dataset, 0 if bf16.
// ---------------------------------------------------------------------------
__global__ __launch_bounds__(1024) void k_detect(
    const float* __restrict__ norm_f, int* __restrict__ flag)
{
    __shared__ int sbad;
    if (threadIdx.x == 0) sbad = 0;
    __syncthreads();
    float v = norm_f[threadIdx.x];
    int bad = (v != v || fabsf(v) > 1e3f) ? 1 : 0;
    if (bad) atomicOr(&sbad, 1);
    __syncthreads();
    if (threadIdx.x == 0) *flag = sbad ? 0 : 1;
}

// ---------------------------------------------------------------------------
// Bucket histogram (proven structure; bucket = dst>>4).
// ---------------------------------------------------------------------------
__global__ __launch_bounds__(256) void k_bhist(
    const int* __restrict__ dst, int* __restrict__ H)
{
    __shared__ int hist[NBKT];
    for (int i = threadIdx.x; i < NBKT; i += 256) hist[i] = 0;
    __syncthreads();
    const int e0 = blockIdx.x * P1_CHUNK;
    for (int i = threadIdx.x; i < P1_CHUNK; i += 256) {
        int e = e0 + i;
        if (e < N_EDGES) atomicAdd(&hist[dst[e] >> BKT_SH], 1);
    }
    __syncthreads();
    for (int b = threadIdx.x; b < NBKT; b += 256)
        H[blockIdx.x * NBKT + b] = hist[b];
}

__global__ __launch_bounds__(256) void k_bscan1(
    const int* __restrict__ H, int* __restrict__ OT, int* __restrict__ tot)
{
    __shared__ int col[P1_GRID];
    const int b = blockIdx.x;
    for (int i = threadIdx.x; i < P1_GRID; i += 256)
        col[i] = H[i * NBKT + b];
    __syncthreads();
    if (threadIdx.x < 64) {
        const int lane = threadIdx.x;
        int carry = 0;
        for (int chunk = 0; chunk < (P1_GRID + 63) / 64; ++chunk) {
            int i = chunk * 64 + lane;
            int c = (i < P1_GRID) ? col[i] : 0;
            int incl = c;
#pragma unroll
            for (int off = 1; off < 64; off <<= 1) {
                int t = __shfl_up(incl, off, 64);
                if (lane >= off) incl += t;
            }
            if (i < P1_GRID) col[i] = carry + incl - c;
            carry += __shfl(incl, 63, 64);
        }
        if (lane == 0) tot[b] = carry;
    }
    __syncthreads();
    for (int i = threadIdx.x; i < P1_GRID; i += 256)
        OT[(size_t)b * P1_GRID + i] = col[i];
}

__global__ __launch_bounds__(64) void k_bscan2(
    const int* __restrict__ tot, int* __restrict__ base)
{
    const int lane = threadIdx.x;
    int carry = 0;
    for (int chunk = 0; chunk < (NBKT + 63) / 64; ++chunk) {
        int i = chunk * 64 + lane;
        int c = (i < NBKT) ? tot[i] : 0;
        int incl = c;
#pragma unroll
        for (int off = 1; off < 64; off <<= 1) {
            int t = __shfl_up(incl, off, 64);
            if (lane >= off) incl += t;
        }
        if (i < NBKT) base[i] = carry + incl - c;
        carry += __shfl(incl, 63, 64);
    }
    if (lane == 0) base[NBKT] = carry;   // == N_EDGES
}

// ---------------------------------------------------------------------------
// P1 (proven): multisplit into bucket runs, deterministic reservation.
// rec: [7:0]=dst&15, [23:8]=src, [27:24]=rel, [47:32]=norm bf16.
// ---------------------------------------------------------------------------
template<int IS_F32>
__device__ __forceinline__ void p1_body(
    const int* __restrict__ src, const int* __restrict__ dst,
    const int* __restrict__ rel, const void* __restrict__ norm_raw,
    const int* __restrict__ base, const int* __restrict__ OT,
    unsigned long long* __restrict__ R, int* curs)
{
    const int blk = blockIdx.x;
    for (int b = threadIdx.x; b < NBKT; b += 256)
        curs[b] = base[b] + OT[(size_t)b * P1_GRID + blk];
    __syncthreads();
    const int e0 = blk * P1_CHUNK;
    for (int i = threadIdx.x; i < P1_CHUNK; i += 256) {
        int e = e0 + i;
        if (e >= N_EDGES) continue;
        int d = dst[e];
        int pos = atomicAdd(&curs[d >> BKT_SH], 1);
        unsigned short nb = f2bfbits(ldx<IS_F32>(norm_raw, e));
        unsigned long long rec =
              (unsigned long long)(d & (BKT_SZ - 1))
            | ((unsigned long long)(unsigned)src[e] << 8)
            | ((unsigned long long)(unsigned)rel[e] << 24)
            | ((unsigned long long)nb << 32);
        R[pos] = rec;
    }
}

__global__ __launch_bounds__(256) void k_p1(
    const int* __restrict__ src, const int* __restrict__ dst,
    const int* __restrict__ rel, const void* __restrict__ norm_raw,
    const int* __restrict__ base, const int* __restrict__ OT,
    unsigned long long* __restrict__ R, const int* __restrict__ flag)
{
    __shared__ int curs[NBKT];
    if (*flag) p1_body<1>(src, dst, rel, norm_raw, base, OT, R, curs);
    else       p1_body<0>(src, dst, rel, norm_raw, base, OT, R, curs);
}

// ---------------------------------------------------------------------------
// P2SEG: per bucket, split run into 16 rel segments, each padded to x32.
// packed2: [7:0]=dstlocal(0..15), [23:8]=src. Pad entries all-zero (norm=0).
// Segment starts 32-aligned (gbase = align32(base[b]) + b*SEG_PAD).
// ---------------------------------------------------------------------------
__global__ __launch_bounds__(256) void k_p2seg(
    const int* __restrict__ base,
    const unsigned long long* __restrict__ R,
    unsigned* __restrict__ packed2,
    unsigned short* __restrict__ normS,
    int* __restrict__ segBase,
    int* __restrict__ segCnt)
{
    __shared__ int cnt[16], curs[16], sbl[16];
    const int tid = threadIdx.x;
    if (tid < 16) { cnt[tid] = 0; curs[tid] = 0; }
    __syncthreads();

    const int b  = blockIdx.x;
    const int c0 = base[b], c1 = base[b + 1];

    for (int i = c0 + tid; i < c1; i += 256)
        atomicAdd(&cnt[(int)((R[i] >> 24) & 15)], 1);
    __syncthreads();

    if (tid == 0) {
        int g = ((c0 + 31) & ~31) + b * SEG_PAD;
        for (int r = 0; r < 16; ++r) {
            sbl[r] = g;
            g += (cnt[r] + 31) & ~31;
        }
    }
    __syncthreads();
    if (tid < 16) {
        segBase[b * 16 + tid] = sbl[tid];
        segCnt[b * 16 + tid]  = cnt[tid];
    }

    for (int i = c0 + tid; i < c1; i += 256) {
        unsigned long long rec = R[i];
        int r = (int)((rec >> 24) & 15);
        int pos = sbl[r] + atomicAdd(&curs[r], 1);
        packed2[pos] = (unsigned)(rec & 0xFFFFFFu);
        normS[pos]   = (unsigned short)(rec >> 32);
    }
    __syncthreads();

    // pads: <=31 per segment, 16 segments -> 512 candidate slots, 2 passes
    for (int p = tid; p < 16 * 32; p += 256) {
        int r = p >> 5, j = p & 31;
        int c = cnt[r], pe = (c + 31) & ~31;
        if (j < pe - c) {
            int pos = sbl[r] + c + j;
            packed2[pos] = 0;
            normS[pos]   = 0;
        }
    }
}

// ---------------------------------------------------------------------------
// PREP (proven): h -> bf16 copy (6.4 MB gather target) and W -> pre-swizzled
// bf16 B-fragment layout (stride 40).
// ---------------------------------------------------------------------------
__global__ __launch_bounds__(256) void k_prep(
    const void* __restrict__ h_raw, const void* __restrict__ w_raw,
    unsigned short* __restrict__ hbf, unsigned short* __restrict__ Wswz,
    const int* __restrict__ flag)
{
    const int f = *flag;
    const int blk = blockIdx.x;
    if (blk < PREP_HBLK) {
        int i0 = blk * 1024 + threadIdx.x * 4;
        if (f) {
            float4 v = *(const float4*)((const float*)h_raw + i0);
            ushort4v o;
            o[0] = f2bfbits(v.x); o[1] = f2bfbits(v.y);
            o[2] = f2bfbits(v.z); o[3] = f2bfbits(v.w);
            *(ushort4v*)(hbf + i0) = o;
        } else {
            *(uint2*)(hbf + i0) = *(const uint2*)((const unsigned short*)h_raw + i0);
        }
    } else {
        int rel = blk - PREP_HBLK;
        for (int idx = threadIdx.x; idx < 4096; idx += 256) {
            int d = idx >> 6, o = idx & 63;
            float wv = f ? ((const float*)w_raw)[(size_t)((rel << 6) + d) * 64 + o]
                         : bfbits2f(((const unsigned short*)w_raw)[(size_t)((rel << 6) + d) * 64 + o]);
            int c = d >> 5, q = (d >> 3) & 3, j = d & 7;
            Wswz[(size_t)rel * 5120 + ((c << 6) + o) * 40 + q * 8 + j] = f2bfbits(wv);
        }
    }
}

// ---------------------------------------------------------------------------
// K_FUSED2: one wave per 16-dst tile. Per rel segment:
//   s[16x64] = sum_chunks P[16x32] x H[32x64]   (P = norm selector; MFMA does
//   the dst-scatter; H rows gathered as 2B loads from 6.4MB L2-scale hbf)
//   out_tile += s @ W_r                          (8 MFMAs, reg accumulation)
// Zero atomics. Fragment layouts identical to harness-proven k1_mfma.
// ---------------------------------------------------------------------------
#define MFMA_BF16 __builtin_amdgcn_mfma_f32_16x16x32_bf16

__global__ __launch_bounds__(256) void k_fused2(
    const unsigned* __restrict__ packed2,
    const unsigned short* __restrict__ normS,
    const unsigned short* __restrict__ hbf,
    const unsigned short* __restrict__ Wswz,
    const int* __restrict__ segBase,
    const int* __restrict__ segCnt,
    void* __restrict__ out, const int* __restrict__ flag)
{
    __shared__ __align__(16) unsigned short sbuf[4][16 * 72];
    const int tid  = threadIdx.x;
    const int lane = tid & 63, wave = tid >> 6;
    const int n15  = lane & 15, quad = lane >> 4;
    const int tile = blockIdx.x * 4 + wave;
    if (tile >= NBKT) return;

    float4v ac0 = {0.f,0.f,0.f,0.f}, ac1 = {0.f,0.f,0.f,0.f};
    float4v ac2 = {0.f,0.f,0.f,0.f}, ac3 = {0.f,0.f,0.f,0.f};
    unsigned short* sb_ = &sbuf[wave][0];

    for (int r = 0; r < NREL; ++r) {
        const int sgb  = segBase[tile * 16 + r];
        const int scnt = segCnt[tile * 16 + r];
        if (scnt == 0) continue;
        const int nch = (scnt + 31) >> 5;

        float4v s0 = {0.f,0.f,0.f,0.f}, s1 = {0.f,0.f,0.f,0.f};
        float4v s2 = {0.f,0.f,0.f,0.f}, s3 = {0.f,0.f,0.f,0.f};

        for (int c = 0; c < nch; ++c) {
            const int e0 = sgb + (c << 5) + (quad << 3);
            const uint4 pa = *(const uint4*)(packed2 + e0);
            const uint4 pb = *(const uint4*)(packed2 + e0 + 4);
            const ushort4v na = *(const ushort4v*)(normS + e0);
            const ushort4v nb = *(const ushort4v*)(normS + e0 + 4);

            const unsigned short* h0 = hbf + (size_t)(pa.x >> 8) * 64 + n15;
            const unsigned short* h1 = hbf + (size_t)(pa.y >> 8) * 64 + n15;
            const unsigned short* h2 = hbf + (size_t)(pa.z >> 8) * 64 + n15;
            const unsigned short* h3 = hbf + (size_t)(pa.w >> 8) * 64 + n15;
            const unsigned short* h4 = hbf + (size_t)(pb.x >> 8) * 64 + n15;
            const unsigned short* h5 = hbf + (size_t)(pb.y >> 8) * 64 + n15;
            const unsigned short* h6 = hbf + (size_t)(pb.z >> 8) * 64 + n15;
            const unsigned short* h7 = hbf + (size_t)(pb.w >> 8) * 64 + n15;

            short8 av;
            av[0] = ((int)(pa.x & 15u) == n15) ? (short)na[0] : (short)0;
            av[1] = ((int)(pa.y & 15u) == n15) ? (short)na[1] : (short)0;
            av[2] = ((int)(pa.z & 15u) == n15) ? (short)na[2] : (short)0;
            av[3] = ((int)(pa.w & 15u) == n15) ? (short)na[3] : (short)0;
            av[4] = ((int)(pb.x & 15u) == n15) ? (short)nb[0] : (short)0;
            av[5] = ((int)(pb.y & 15u) == n15) ? (short)nb[1] : (short)0;
            av[6] = ((int)(pb.z & 15u) == n15) ? (short)nb[2] : (short)0;
            av[7] = ((int)(pb.w & 15u) == n15) ? (short)nb[3] : (short)0;

#define GATHER_MFMA(S, OFF) \
            { short8 bv; \
              bv[0] = (short)h0[OFF]; bv[1] = (short)h1[OFF]; \
              bv[2] = (short)h2[OFF]; bv[3] = (short)h3[OFF]; \
              bv[4] = (short)h4[OFF]; bv[5] = (short)h5[OFF]; \
              bv[6] = (short)h6[OFF]; bv[7] = (short)h7[OFF]; \
              S = MFMA_BF16(av, bv, S, 0, 0, 0); }

            GATHER_MFMA(s0, 0)
            GATHER_MFMA(s1, 16)
            GATHER_MFMA(s2, 32)
            GATHER_MFMA(s3, 48)
#undef GATHER_MFMA
        }

        // repack s (C layout: row=quad*4+i, col=t*16+n15) -> LDS row-major
#pragma unroll
        for (int i = 0; i < 4; ++i) {
            sb_[(quad * 4 + i) * 72 +  0 + n15] = f2bfbits(s0[i]);
            sb_[(quad * 4 + i) * 72 + 16 + n15] = f2bfbits(s1[i]);
            sb_[(quad * 4 + i) * 72 + 32 + n15] = f2bfbits(s2[i]);
            sb_[(quad * 4 + i) * 72 + 48 + n15] = f2bfbits(s3[i]);
        }

        // A-frags: row=n15, k-chunk=quad (k1-proven layout)
        const short8 a0 = *(const short8*)(sb_ + n15 * 72 + quad * 8);
        const short8 a1 = *(const short8*)(sb_ + n15 * 72 + 32 + quad * 8);

        const unsigned short* wp = Wswz + (size_t)r * 5120;
        const short8 w00 = *(const short8*)(wp + ( 0 + n15) * 40 + quad * 8);
        const short8 w01 = *(const short8*)(wp + (16 + n15) * 40 + quad * 8);
        const short8 w02 = *(const short8*)(wp + (32 + n15) * 40 + quad * 8);
        const short8 w03 = *(const short8*)(wp + (48 + n15) * 40 + quad * 8);
        const short8 w10 = *(const short8*)(wp + (64 + n15) * 40 + quad * 8);
        const short8 w11 = *(const short8*)(wp + (80 + n15) * 40 + quad * 8);
        const short8 w12 = *(const short8*)(wp + (96 + n15) * 40 + quad * 8);
        const short8 w13 = *(const short8*)(wp + (112 + n15) * 40 + quad * 8);

        ac0 = MFMA_BF16(a0, w00, ac0, 0, 0, 0);
        ac1 = MFMA_BF16(a0, w01, ac1, 0, 0, 0);
        ac2 = MFMA_BF16(a0, w02, ac2, 0, 0, 0);
        ac3 = MFMA_BF16(a0, w03, ac3, 0, 0, 0);
        ac0 = MFMA_BF16(a1, w10, ac0, 0, 0, 0);
        ac1 = MFMA_BF16(a1, w11, ac1, 0, 0, 0);
        ac2 = MFMA_BF16(a1, w12, ac2, 0, 0, 0);
        ac3 = MFMA_BF16(a1, w13, ac3, 0, 0, 0);
    }

    const int node0 = tile << 4;
    const int f = *flag;
#define STORE_T(AC, T) \
    { \
        _Pragma("unroll") \
        for (int i = 0; i < 4; ++i) { \
            float rv = fmaxf(AC[i], 0.f); \
            size_t ob = (size_t)(node0 + quad * 4 + i) * 64 + (T) * 16 + n15; \
            if (f) ((float*)out)[ob] = rv; \
            else   ((unsigned short*)out)[ob] = f2bfbits(rv); \
        } \
    }
    STORE_T(ac0, 0)
    STORE_T(ac1, 1)
    STORE_T(ac2, 2)
    STORE_T(ac3, 3)
#undef STORE_T
}

// ---------------------------------------------------------------------------
extern "C" void kernel_launch(void* const* d_in, const int* in_sizes, int n_in,
                              void* d_out, int out_size, void* d_ws, size_t ws_size,
                              hipStream_t stream)
{
    const void* h      = d_in[0];
    const void* weight = d_in[1];
    const void* norm   = d_in[2];
    const int* src = (const int*)d_in[3];
    const int* dst = (const int*)d_in[4];
    const int* rel = (const int*)d_in[5];

    char* w = (char*)d_ws;
    int* flag = (int*)w;                        w += 256;
    int* base = (int*)w;                        w += ((NBKT + 1) * 4 + 255) / 256 * 256;
    int* tot  = (int*)w;                        w += (NBKT * 4 + 255) / 256 * 256;
    int* H    = (int*)w;                        w += ((size_t)P1_GRID * NBKT * 4 + 255) / 256 * 256;
    int* OT   = (int*)w;                        w += ((size_t)NBKT * P1_GRID * 4 + 255) / 256 * 256;
    int* segBase = (int*)w;                     w += ((size_t)NBKT * 16 * 4 + 255) / 256 * 256;
    int* segCnt  = (int*)w;                     w += ((size_t)NBKT * 16 * 4 + 255) / 256 * 256;
    unsigned long long* R = (unsigned long long*)w;  w += (size_t)N_EDGES * 8;
    unsigned* packed2 = (unsigned*)w;           w += (size_t)EMAX * 4;
    unsigned short* normS = (unsigned short*)w; w += (size_t)EMAX * 2;
    unsigned short* hbf = (unsigned short*)w;   w += (size_t)N_NODES * DIM * 2;
    unsigned short* Wswz = (unsigned short*)w;  w += (size_t)NREL * 5120 * 2;

    k_detect<<<1, 1024, 0, stream>>>((const float*)norm, flag);

    k_bhist<<<P1_GRID, 256, 0, stream>>>(dst, H);
    k_bscan1<<<NBKT, 256, 0, stream>>>(H, OT, tot);
    k_bscan2<<<1, 64, 0, stream>>>(tot, base);

    k_p1<<<P1_GRID, 256, 0, stream>>>(src, dst, rel, norm, base, OT, R, flag);
    k_p2seg<<<NBKT, 256, 0, stream>>>(base, R, packed2, normS, segBase, segCnt);

    k_prep<<<PREP_HBLK + NREL, 256, 0, stream>>>(h, weight, hbf, Wswz, flag);

    k_fused2<<<(NBKT + 3) / 4, 256, 0, stream>>>(packed2, normS, hbf, Wswz,
                                                 segBase, segCnt, d_out, flag);
}